// Round 5
// baseline (57.206 us; speedup 1.0000x reference)
//
#include <hip/hip_runtime.h>

// Fused: conv3x3(6ch, VALID) + relu + shifted-product edge logic + 2x2 mean pool.
// x: (1,1,2048,2048) f32, w: (6,1,3,3) f32
// out: concat[ mult_x (12,2046,2046) f32 , pooled (12,1023,1023) f32 ]
//
// R5 = R4 + alignment-aware stores:
//   mult row stride 8184B => odd rows are only 8B-aligned: use 2x dwordx2
//   (never straddles a 64B line) instead of a straddling dwordx4.
//   pooled plane stride 1023^2 (odd) => v2f only when (k+qy) even, else 2x dword.

static constexpr int XD = 2048;   // input dim
static constexpr int HF = 2046;   // conv-valid output dim
static constexpr int HP = 1023;   // pooled dim
static constexpr float THR = 0.01f;

typedef float v4f __attribute__((ext_vector_type(4), aligned(4)));
typedef float v2f __attribute__((ext_vector_type(2), aligned(4)));

// conv+relu for channels CA,CB over the 3x5 site patch from the 5x8 window.
// cR: site row 2 (global fr+2==2046) invalid -> copy site row 1 (self-clamp).
// cC: site cols 2..4 (global >=2046) invalid -> copy site col 1.
template<int CA, int CB>
__device__ __forceinline__ void conv_pair(const float (&win)[5][8],
                                          const float* __restrict__ w,
                                          bool cR, bool cC,
                                          float (&fA)[3][5], float (&fB)[3][5])
{
#pragma unroll
    for (int sr = 0; sr < 3; ++sr)
#pragma unroll
        for (int sc = 0; sc < 5; ++sc) {
            float a = 0.f, b = 0.f;
#pragma unroll
            for (int ki = 0; ki < 3; ++ki)
#pragma unroll
                for (int kj = 0; kj < 3; ++kj) {
                    const float xv = win[sr + ki][sc + kj];
                    a = fmaf(xv, w[CA * 9 + ki * 3 + kj], a);
                    b = fmaf(xv, w[CB * 9 + ki * 3 + kj], b);
                }
            fA[sr][sc] = fmaxf(a, 0.f);
            fB[sr][sc] = fmaxf(b, 0.f);
        }
    // row fixup first, then col (corner thread gets both -> fA[2][>=2]=fA[1][1])
#pragma unroll
    for (int sc = 0; sc < 5; ++sc) {
        fA[2][sc] = cR ? fA[1][sc] : fA[2][sc];
        fB[2][sc] = cR ? fB[1][sc] : fB[2][sc];
    }
#pragma unroll
    for (int sr = 0; sr < 3; ++sr)
#pragma unroll
        for (int sc = 2; sc < 5; ++sc) {
            fA[sr][sc] = cC ? fA[sr][1] : fA[sr][sc];
            fB[sr][sc] = cC ? fB[sr][1] : fB[sr][sc];
        }
}

// One branch (V,H channel pair) -> planes KB..KB+5 for the 2x4 strip.
template<int CV, int CH, int KB>
__device__ __forceinline__ void branch_eval(
    const float (&win)[5][8], const float* __restrict__ w, unsigned mb,
    bool cR, bool cC, bool rowsValid, int fr, int fc0, int qy, int pc0,
    float* __restrict__ mult, float* __restrict__ pooled)
{
    float fV[3][5], fH[3][5];
    conv_pair<CV, CH>(win, w, cR, cC, fV, fH);

    float pl[6][2];
#pragma unroll
    for (int k = 0; k < 6; ++k) { pl[k][0] = 0.f; pl[k][1] = 0.f; }

#pragma unroll
    for (int py = 0; py < 2; ++py) {
        float o[6][4];
#pragma unroll
        for (int px = 0; px < 4; ++px) {
            const bool z0 = cR && (py == 0);   // r == HF-2: shift0 row -> 0
            const bool z1 = cC && (px == 0);   // c == HF-2: shift1 col -> 0
            const float v = fV[py][px], h = fH[py][px];
            const float vs0  = z0 ? 0.f : fV[py + 1][px];
            const float hs0  = z0 ? 0.f : fH[py + 1][px];
            const float vs1  = z1 ? 0.f : fV[py][px + 1];
            const float hs1  = z1 ? 0.f : fH[py][px + 1];
            const float vs01 = (z0 || z1) ? 0.f : fV[py + 1][px + 1];
            const float hs01 = (z0 || z1) ? 0.f : fH[py + 1][px + 1];
            const float vert  = vs0 * v;
            const float horiz = hs1 * h;
            const int base = py * 4 + px;
            o[0][px] = (vert  <= THR) ? horiz : 0.f;
            o[1][px] = ((mb >> base)        & 1u) ? vs01 * v   : 0.f;
            o[2][px] = (horiz <= THR) ? vert  : 0.f;
            o[3][px] = ((mb >> (8  + base)) & 1u) ? vs0 * vs1  : 0.f;
            o[4][px] = ((mb >> (16 + base)) & 1u) ? hs01 * h   : 0.f;
            o[5][px] = ((mb >> (24 + base)) & 1u) ? hs0 * hs1  : 0.f;
        }
        if (rowsValid) {
            float* mrow = mult + (size_t)(fr + py) * HF + fc0;
            if (cC) {   // only cols 2044,2045 exist (8B-aligned always)
#pragma unroll
                for (int k = 0; k < 6; ++k) {
                    v2f val; val[0] = o[k][0]; val[1] = o[k][1];
                    *reinterpret_cast<v2f*>(mrow + (size_t)(KB + k) * HF * HF) = val;
                }
            } else if (py == 0) {
                // even row: base 16B-aligned -> dwordx4
#pragma unroll
                for (int k = 0; k < 6; ++k) {
                    v4f val;
                    val[0] = o[k][0]; val[1] = o[k][1];
                    val[2] = o[k][2]; val[3] = o[k][3];
                    *reinterpret_cast<v4f*>(mrow + (size_t)(KB + k) * HF * HF) = val;
                }
            } else {
                // odd row: base only 8B-aligned -> two dwordx2 (no line straddle)
#pragma unroll
                for (int k = 0; k < 6; ++k) {
                    float* p = mrow + (size_t)(KB + k) * HF * HF;
                    v2f lo; lo[0] = o[k][0]; lo[1] = o[k][1];
                    v2f hi; hi[0] = o[k][2]; hi[1] = o[k][3];
                    *reinterpret_cast<v2f*>(p)     = lo;
                    *reinterpret_cast<v2f*>(p + 2) = hi;
                }
            }
        }
#pragma unroll
        for (int k = 0; k < 6; ++k) {
            pl[k][0] += o[k][0] + o[k][1];
            pl[k][1] += o[k][2] + o[k][3];
        }
    }
    if (rowsValid) {
#pragma unroll
        for (int k = 0; k < 6; ++k) {
            float* pp = pooled + (size_t)(KB + k) * HP * HP + (size_t)qy * HP + pc0;
            if (cC) {
                *pp = 0.25f * pl[k][0];   // second pool cell (1023) is OOB
            } else if ((((KB + k) + qy) & 1) == 0) {
                // plane stride 1023^2 is odd: 8B-aligned iff (k+qy) even
                v2f val; val[0] = 0.25f * pl[k][0]; val[1] = 0.25f * pl[k][1];
                *reinterpret_cast<v2f*>(pp) = val;
            } else {
                pp[0] = 0.25f * pl[k][0];
                pp[1] = 0.25f * pl[k][1];
            }
        }
    }
}

__global__ __launch_bounds__(256) void first_level_fused(
    const float* __restrict__ x,
    const float* __restrict__ w,
    float* __restrict__ out)
{
    // Block tile: output rows [R0, R0+8) (2 per ty), cols [C0, C0+256) (4 per tx).
    // Input needed: rows R0..R0+10 (11), cols C0..C0+258 (259) -> LDS [11][260].
    __shared__ float xs[11][260];

    const int tx = threadIdx.x;            // 0..63 (one wave per ty)
    const int ty = threadIdx.y;            // 0..3
    const int tid = ty * 64 + tx;
    const int R0 = blockIdx.y * 8;
    const int C0 = blockIdx.x * 256;

#pragma unroll
    for (int it = 0; it < 12; ++it) {
        const int idx = tid + it * 256;
        if (idx < 11 * 259) {
            const int lr = idx / 259;
            const int lc = idx - lr * 259;
            const int gr = min(R0 + lr, XD - 1);
            const int gc = min(C0 + lc, XD - 1);
            xs[lr][lc] = x[gr * XD + gc];
        }
    }
    __syncthreads();

    const int fr  = R0 + 2 * ty;           // first output row (always even)
    const int fc0 = C0 + 4 * tx;           // first output col
    const int qy  = fr >> 1;               // pooled row
    const int pc0 = fc0 >> 1;              // first pooled col
    const bool rowsValid = (fr < HF);
    const bool cR = (fr  == HF - 2);       // site row 2 == 2046 -> clamp
    const bool cC = (fc0 == HF - 2);       // site cols >= 2046 -> clamp

    // 5x8 input window from LDS: rows 2ty..2ty+4, cols 4tx..4tx+7
    float win[5][8];
#pragma unroll
    for (int i = 0; i < 5; ++i) {
        const v4f a = *reinterpret_cast<const v4f*>(&xs[2 * ty + i][4 * tx]);
        const v4f b = *reinterpret_cast<const v4f*>(&xs[2 * ty + i][4 * tx + 4]);
        win[i][0] = a[0]; win[i][1] = a[1]; win[i][2] = a[2]; win[i][3] = a[3];
        win[i][4] = b[0]; win[i][5] = b[1]; win[i][6] = b[2]; win[i][7] = b[3];
    }

    // Suppression masks from D1 (ch4), D2 (ch5), bit-packed:
    // bit layout: m*8 + py*4 + px for m in {fd, sd, fdd, sdd}
    unsigned mb = 0;
    {
        float d1[3][5], d2[3][5];
        conv_pair<4, 5>(win, w, cR, cC, d1, d2);
#pragma unroll
        for (int py = 0; py < 2; ++py)
#pragma unroll
            for (int px = 0; px < 4; ++px) {
                const bool z0 = cR && (py == 0);
                const bool z1 = cC && (px == 0);
                const float a1 = d1[py][px], a2 = d2[py][px];
                const float s11 = z1 ? 0.f : d1[py][px + 1];
                const float s12 = z1 ? 0.f : d2[py][px + 1];
                const float s01 = z0 ? 0.f : d1[py + 1][px];
                const float s02 = z0 ? 0.f : d2[py + 1][px];
                const int base = py * 4 + px;
                mb |= (a1 * s11 <= THR ? 1u : 0u) << base;
                mb |= (a2 * s12 <= THR ? 1u : 0u) << (8 + base);
                mb |= (a1 * s01 <= THR ? 1u : 0u) << (16 + base);
                mb |= (a2 * s02 <= THR ? 1u : 0u) << (24 + base);
            }
    }

    float* __restrict__ mult   = out;
    float* __restrict__ pooled = out + (size_t)12 * HF * HF;

    // branch a: V1=ch0, H1=ch2 -> planes 0..5; branch b: oV1=ch1, oH1=ch3 -> 6..11
    branch_eval<0, 2, 0>(win, w, mb, cR, cC, rowsValid, fr, fc0, qy, pc0,
                         mult, pooled);
    branch_eval<1, 3, 6>(win, w, mb, cR, cC, rowsValid, fr, fc0, qy, pc0,
                         mult, pooled);
}

extern "C" void kernel_launch(void* const* d_in, const int* in_sizes, int n_in,
                              void* d_out, int out_size, void* d_ws, size_t ws_size,
                              hipStream_t stream) {
    const float* x = (const float*)d_in[0];
    const float* w = (const float*)d_in[1];
    float* out = (float*)d_out;
    (void)in_sizes; (void)n_in; (void)out_size; (void)d_ws; (void)ws_size;

    dim3 block(64, 4);
    dim3 grid(8, 256);   // x: 8*256=2048 cols >= 2046 ; y: 256*8=2048 rows >= 2046
    hipLaunchKernelGGL(first_level_fused, grid, block, 0, stream, x, w, out);
}

// Round 6
// 49.155 us; speedup vs baseline: 1.1638x; 1.1638x over previous
//
#include <hip/hip_runtime.h>

// Fused: conv3x3(6ch, VALID) + relu + shifted-product edge logic + 2x2 mean pool.
// x: (1,1,2048,2048) f32, w: (6,1,3,3) f32
// out: concat[ mult_x (12,2046,2046) f32 , pooled (12,1023,1023) f32 ]
//
// R6 = R4 (52.4us base: 64x4 blocks, 2x4 strip/thread, dwordx4 mult stores,
// LDS-staged input, channel-pair conv, bit-packed masks) + XCD-aware block
// remap: XCD k (= bid%8) owns a contiguous 32-band row region with all 8
// column-blocks of each band -> partial 64B lines at segment seams merge in
// one XCD's L2 instead of splitting across two non-coherent L2s.

static constexpr int XD = 2048;   // input dim
static constexpr int HF = 2046;   // conv-valid output dim
static constexpr int HP = 1023;   // pooled dim
static constexpr float THR = 0.01f;

typedef float v4f __attribute__((ext_vector_type(4), aligned(4)));
typedef float v2f __attribute__((ext_vector_type(2), aligned(4)));

// conv+relu for channels CA,CB over the 3x5 site patch from the 5x8 window.
// cR: site row 2 (global fr+2==2046) invalid -> copy site row 1 (self-clamp).
// cC: site cols 2..4 (global >=2046) invalid -> copy site col 1.
template<int CA, int CB>
__device__ __forceinline__ void conv_pair(const float (&win)[5][8],
                                          const float* __restrict__ w,
                                          bool cR, bool cC,
                                          float (&fA)[3][5], float (&fB)[3][5])
{
#pragma unroll
    for (int sr = 0; sr < 3; ++sr)
#pragma unroll
        for (int sc = 0; sc < 5; ++sc) {
            float a = 0.f, b = 0.f;
#pragma unroll
            for (int ki = 0; ki < 3; ++ki)
#pragma unroll
                for (int kj = 0; kj < 3; ++kj) {
                    const float xv = win[sr + ki][sc + kj];
                    a = fmaf(xv, w[CA * 9 + ki * 3 + kj], a);
                    b = fmaf(xv, w[CB * 9 + ki * 3 + kj], b);
                }
            fA[sr][sc] = fmaxf(a, 0.f);
            fB[sr][sc] = fmaxf(b, 0.f);
        }
    // row fixup first, then col (corner thread gets both -> fA[2][>=2]=fA[1][1])
#pragma unroll
    for (int sc = 0; sc < 5; ++sc) {
        fA[2][sc] = cR ? fA[1][sc] : fA[2][sc];
        fB[2][sc] = cR ? fB[1][sc] : fB[2][sc];
    }
#pragma unroll
    for (int sr = 0; sr < 3; ++sr)
#pragma unroll
        for (int sc = 2; sc < 5; ++sc) {
            fA[sr][sc] = cC ? fA[sr][1] : fA[sr][sc];
            fB[sr][sc] = cC ? fB[sr][1] : fB[sr][sc];
        }
}

// One branch (V,H channel pair) -> planes KB..KB+5 for the 2x4 strip.
template<int CV, int CH, int KB>
__device__ __forceinline__ void branch_eval(
    const float (&win)[5][8], const float* __restrict__ w, unsigned mb,
    bool cR, bool cC, bool rowsValid, int fr, int fc0, int qy, int pc0,
    float* __restrict__ mult, float* __restrict__ pooled)
{
    float fV[3][5], fH[3][5];
    conv_pair<CV, CH>(win, w, cR, cC, fV, fH);

    float pl[6][2];
#pragma unroll
    for (int k = 0; k < 6; ++k) { pl[k][0] = 0.f; pl[k][1] = 0.f; }

#pragma unroll
    for (int py = 0; py < 2; ++py) {
        float o[6][4];
#pragma unroll
        for (int px = 0; px < 4; ++px) {
            const bool z0 = cR && (py == 0);   // r == HF-2: shift0 row -> 0
            const bool z1 = cC && (px == 0);   // c == HF-2: shift1 col -> 0
            const float v = fV[py][px], h = fH[py][px];
            const float vs0  = z0 ? 0.f : fV[py + 1][px];
            const float hs0  = z0 ? 0.f : fH[py + 1][px];
            const float vs1  = z1 ? 0.f : fV[py][px + 1];
            const float hs1  = z1 ? 0.f : fH[py][px + 1];
            const float vs01 = (z0 || z1) ? 0.f : fV[py + 1][px + 1];
            const float hs01 = (z0 || z1) ? 0.f : fH[py + 1][px + 1];
            const float vert  = vs0 * v;
            const float horiz = hs1 * h;
            const int base = py * 4 + px;
            o[0][px] = (vert  <= THR) ? horiz : 0.f;
            o[1][px] = ((mb >> base)        & 1u) ? vs01 * v   : 0.f;
            o[2][px] = (horiz <= THR) ? vert  : 0.f;
            o[3][px] = ((mb >> (8  + base)) & 1u) ? vs0 * vs1  : 0.f;
            o[4][px] = ((mb >> (16 + base)) & 1u) ? hs01 * h   : 0.f;
            o[5][px] = ((mb >> (24 + base)) & 1u) ? hs0 * hs1  : 0.f;
        }
        if (rowsValid) {
            float* mrow = mult + (size_t)(fr + py) * HF + fc0;
            if (cC) {   // only cols 2044,2045 exist
#pragma unroll
                for (int k = 0; k < 6; ++k) {
                    v2f val; val[0] = o[k][0]; val[1] = o[k][1];
                    *reinterpret_cast<v2f*>(mrow + (size_t)(KB + k) * HF * HF) = val;
                }
            } else {
#pragma unroll
                for (int k = 0; k < 6; ++k) {
                    v4f val;
                    val[0] = o[k][0]; val[1] = o[k][1];
                    val[2] = o[k][2]; val[3] = o[k][3];
                    *reinterpret_cast<v4f*>(mrow + (size_t)(KB + k) * HF * HF) = val;
                }
            }
        }
#pragma unroll
        for (int k = 0; k < 6; ++k) {
            pl[k][0] += o[k][0] + o[k][1];
            pl[k][1] += o[k][2] + o[k][3];
        }
    }
    if (rowsValid) {
#pragma unroll
        for (int k = 0; k < 6; ++k) {
            float* pp = pooled + (size_t)(KB + k) * HP * HP + (size_t)qy * HP + pc0;
            if (cC) {
                *pp = 0.25f * pl[k][0];   // second pool cell (1023) is OOB
            } else {
                v2f val; val[0] = 0.25f * pl[k][0]; val[1] = 0.25f * pl[k][1];
                *reinterpret_cast<v2f*>(pp) = val;
            }
        }
    }
}

__global__ __launch_bounds__(256) void first_level_fused(
    const float* __restrict__ x,
    const float* __restrict__ w,
    float* __restrict__ out)
{
    // XCD-aware remap of the 1-D grid (2048 blocks) onto (x: 8 col-blocks,
    // y: 256 row-bands). Dispatch round-robins bid%8 across the 8 XCDs, so:
    //   k = bid & 7  (XCD), j = bid >> 3,
    //   x = j & 7, y = k*32 + (j >> 3)
    // gives XCD k the contiguous bands [32k, 32k+32) with all 8 col-blocks of
    // each band -> seam lines merge within one L2, vertical halos hit L2.
    const int bid = blockIdx.x;
    const int k_xcd = bid & 7;
    const int j = bid >> 3;
    const int bx = j & 7;
    const int by = (k_xcd << 5) | (j >> 3);

    // Block tile: output rows [R0, R0+8) (2 per ty), cols [C0, C0+256) (4 per tx).
    // Input needed: rows R0..R0+10 (11), cols C0..C0+258 (259) -> LDS [11][260].
    __shared__ float xs[11][260];

    const int tx = threadIdx.x;            // 0..63 (one wave per ty)
    const int ty = threadIdx.y;            // 0..3
    const int tid = ty * 64 + tx;
    const int R0 = by * 8;
    const int C0 = bx * 256;

#pragma unroll
    for (int it = 0; it < 12; ++it) {
        const int idx = tid + it * 256;
        if (idx < 11 * 259) {
            const int lr = idx / 259;
            const int lc = idx - lr * 259;
            const int gr = min(R0 + lr, XD - 1);
            const int gc = min(C0 + lc, XD - 1);
            xs[lr][lc] = x[gr * XD + gc];
        }
    }
    __syncthreads();

    const int fr  = R0 + 2 * ty;           // first output row (always even)
    const int fc0 = C0 + 4 * tx;           // first output col
    const int qy  = fr >> 1;               // pooled row
    const int pc0 = fc0 >> 1;              // first pooled col
    const bool rowsValid = (fr < HF);
    const bool cR = (fr  == HF - 2);       // site row 2 == 2046 -> clamp
    const bool cC = (fc0 == HF - 2);       // site cols >= 2046 -> clamp

    // 5x8 input window from LDS: rows 2ty..2ty+4, cols 4tx..4tx+7
    float win[5][8];
#pragma unroll
    for (int i = 0; i < 5; ++i) {
        const v4f a = *reinterpret_cast<const v4f*>(&xs[2 * ty + i][4 * tx]);
        const v4f b = *reinterpret_cast<const v4f*>(&xs[2 * ty + i][4 * tx + 4]);
        win[i][0] = a[0]; win[i][1] = a[1]; win[i][2] = a[2]; win[i][3] = a[3];
        win[i][4] = b[0]; win[i][5] = b[1]; win[i][6] = b[2]; win[i][7] = b[3];
    }

    // Suppression masks from D1 (ch4), D2 (ch5), bit-packed:
    // bit layout: m*8 + py*4 + px for m in {fd, sd, fdd, sdd}
    unsigned mb = 0;
    {
        float d1[3][5], d2[3][5];
        conv_pair<4, 5>(win, w, cR, cC, d1, d2);
#pragma unroll
        for (int py = 0; py < 2; ++py)
#pragma unroll
            for (int px = 0; px < 4; ++px) {
                const bool z0 = cR && (py == 0);
                const bool z1 = cC && (px == 0);
                const float a1 = d1[py][px], a2 = d2[py][px];
                const float s11 = z1 ? 0.f : d1[py][px + 1];
                const float s12 = z1 ? 0.f : d2[py][px + 1];
                const float s01 = z0 ? 0.f : d1[py + 1][px];
                const float s02 = z0 ? 0.f : d2[py + 1][px];
                const int base = py * 4 + px;
                mb |= (a1 * s11 <= THR ? 1u : 0u) << base;
                mb |= (a2 * s12 <= THR ? 1u : 0u) << (8 + base);
                mb |= (a1 * s01 <= THR ? 1u : 0u) << (16 + base);
                mb |= (a2 * s02 <= THR ? 1u : 0u) << (24 + base);
            }
    }

    float* __restrict__ mult   = out;
    float* __restrict__ pooled = out + (size_t)12 * HF * HF;

    // branch a: V1=ch0, H1=ch2 -> planes 0..5; branch b: oV1=ch1, oH1=ch3 -> 6..11
    branch_eval<0, 2, 0>(win, w, mb, cR, cC, rowsValid, fr, fc0, qy, pc0,
                         mult, pooled);
    branch_eval<1, 3, 6>(win, w, mb, cR, cC, rowsValid, fr, fc0, qy, pc0,
                         mult, pooled);
}

extern "C" void kernel_launch(void* const* d_in, const int* in_sizes, int n_in,
                              void* d_out, int out_size, void* d_ws, size_t ws_size,
                              hipStream_t stream) {
    const float* x = (const float*)d_in[0];
    const float* w = (const float*)d_in[1];
    float* out = (float*)d_out;
    (void)in_sizes; (void)n_in; (void)out_size; (void)d_ws; (void)ws_size;

    dim3 block(64, 4);
    dim3 grid(2048);   // 1-D; remapped in-kernel to (8 col-blocks, 256 bands)
    hipLaunchKernelGGL(first_level_fused, grid, block, 0, stream, x, w, out);
}

// Round 7
// 48.997 us; speedup vs baseline: 1.1676x; 1.0032x over previous
//
#include <hip/hip_runtime.h>

// Fused: conv3x3(6ch, VALID) + relu + shifted-product edge logic + 2x2 mean pool.
// x: (1,1,2048,2048) f32, w: (6,1,3,3) f32
// out: concat[ mult_x (12,2046,2046) f32 , pooled (12,1023,1023) f32 ]
//
// R7 = R6 (49.2us: 2x4 strip/thread, dwordx4 mult stores, LDS staging,
// channel-pair conv, bit-packed masks, XCD-banded block map) with the y-band
// doubled: 64x8 blocks (512 thr), 16 output rows/block, grid 1024.
// Halo read amplification 11/8 -> 19/16; half the blocks/barriers.

static constexpr int XD = 2048;   // input dim
static constexpr int HF = 2046;   // conv-valid output dim
static constexpr int HP = 1023;   // pooled dim
static constexpr float THR = 0.01f;

typedef float v4f __attribute__((ext_vector_type(4), aligned(4)));
typedef float v2f __attribute__((ext_vector_type(2), aligned(4)));

// conv+relu for channels CA,CB over the 3x5 site patch from the 5x8 window.
// cR: site row 2 (global fr+2==2046) invalid -> copy site row 1 (self-clamp).
// cC: site cols 2..4 (global >=2046) invalid -> copy site col 1.
template<int CA, int CB>
__device__ __forceinline__ void conv_pair(const float (&win)[5][8],
                                          const float* __restrict__ w,
                                          bool cR, bool cC,
                                          float (&fA)[3][5], float (&fB)[3][5])
{
#pragma unroll
    for (int sr = 0; sr < 3; ++sr)
#pragma unroll
        for (int sc = 0; sc < 5; ++sc) {
            float a = 0.f, b = 0.f;
#pragma unroll
            for (int ki = 0; ki < 3; ++ki)
#pragma unroll
                for (int kj = 0; kj < 3; ++kj) {
                    const float xv = win[sr + ki][sc + kj];
                    a = fmaf(xv, w[CA * 9 + ki * 3 + kj], a);
                    b = fmaf(xv, w[CB * 9 + ki * 3 + kj], b);
                }
            fA[sr][sc] = fmaxf(a, 0.f);
            fB[sr][sc] = fmaxf(b, 0.f);
        }
    // row fixup first, then col (corner thread gets both -> fA[2][>=2]=fA[1][1])
#pragma unroll
    for (int sc = 0; sc < 5; ++sc) {
        fA[2][sc] = cR ? fA[1][sc] : fA[2][sc];
        fB[2][sc] = cR ? fB[1][sc] : fB[2][sc];
    }
#pragma unroll
    for (int sr = 0; sr < 3; ++sr)
#pragma unroll
        for (int sc = 2; sc < 5; ++sc) {
            fA[sr][sc] = cC ? fA[sr][1] : fA[sr][sc];
            fB[sr][sc] = cC ? fB[sr][1] : fB[sr][sc];
        }
}

// One branch (V,H channel pair) -> planes KB..KB+5 for the 2x4 strip.
template<int CV, int CH, int KB>
__device__ __forceinline__ void branch_eval(
    const float (&win)[5][8], const float* __restrict__ w, unsigned mb,
    bool cR, bool cC, bool rowsValid, int fr, int fc0, int qy, int pc0,
    float* __restrict__ mult, float* __restrict__ pooled)
{
    float fV[3][5], fH[3][5];
    conv_pair<CV, CH>(win, w, cR, cC, fV, fH);

    float pl[6][2];
#pragma unroll
    for (int k = 0; k < 6; ++k) { pl[k][0] = 0.f; pl[k][1] = 0.f; }

#pragma unroll
    for (int py = 0; py < 2; ++py) {
        float o[6][4];
#pragma unroll
        for (int px = 0; px < 4; ++px) {
            const bool z0 = cR && (py == 0);   // r == HF-2: shift0 row -> 0
            const bool z1 = cC && (px == 0);   // c == HF-2: shift1 col -> 0
            const float v = fV[py][px], h = fH[py][px];
            const float vs0  = z0 ? 0.f : fV[py + 1][px];
            const float hs0  = z0 ? 0.f : fH[py + 1][px];
            const float vs1  = z1 ? 0.f : fV[py][px + 1];
            const float hs1  = z1 ? 0.f : fH[py][px + 1];
            const float vs01 = (z0 || z1) ? 0.f : fV[py + 1][px + 1];
            const float hs01 = (z0 || z1) ? 0.f : fH[py + 1][px + 1];
            const float vert  = vs0 * v;
            const float horiz = hs1 * h;
            const int base = py * 4 + px;
            o[0][px] = (vert  <= THR) ? horiz : 0.f;
            o[1][px] = ((mb >> base)        & 1u) ? vs01 * v   : 0.f;
            o[2][px] = (horiz <= THR) ? vert  : 0.f;
            o[3][px] = ((mb >> (8  + base)) & 1u) ? vs0 * vs1  : 0.f;
            o[4][px] = ((mb >> (16 + base)) & 1u) ? hs01 * h   : 0.f;
            o[5][px] = ((mb >> (24 + base)) & 1u) ? hs0 * hs1  : 0.f;
        }
        if (rowsValid) {
            float* mrow = mult + (size_t)(fr + py) * HF + fc0;
            if (cC) {   // only cols 2044,2045 exist
#pragma unroll
                for (int k = 0; k < 6; ++k) {
                    v2f val; val[0] = o[k][0]; val[1] = o[k][1];
                    *reinterpret_cast<v2f*>(mrow + (size_t)(KB + k) * HF * HF) = val;
                }
            } else {
#pragma unroll
                for (int k = 0; k < 6; ++k) {
                    v4f val;
                    val[0] = o[k][0]; val[1] = o[k][1];
                    val[2] = o[k][2]; val[3] = o[k][3];
                    *reinterpret_cast<v4f*>(mrow + (size_t)(KB + k) * HF * HF) = val;
                }
            }
        }
#pragma unroll
        for (int k = 0; k < 6; ++k) {
            pl[k][0] += o[k][0] + o[k][1];
            pl[k][1] += o[k][2] + o[k][3];
        }
    }
    if (rowsValid) {
#pragma unroll
        for (int k = 0; k < 6; ++k) {
            float* pp = pooled + (size_t)(KB + k) * HP * HP + (size_t)qy * HP + pc0;
            if (cC) {
                *pp = 0.25f * pl[k][0];   // second pool cell (1023) is OOB
            } else {
                v2f val; val[0] = 0.25f * pl[k][0]; val[1] = 0.25f * pl[k][1];
                *reinterpret_cast<v2f*>(pp) = val;
            }
        }
    }
}

__global__ __launch_bounds__(512) void first_level_fused(
    const float* __restrict__ x,
    const float* __restrict__ w,
    float* __restrict__ out)
{
    // XCD-aware remap of the 1-D grid (1024 blocks) onto (x: 8 col-blocks,
    // y: 128 row-bands of 16 rows). Dispatch round-robins bid%8 across XCDs:
    //   k = bid & 7 (XCD), j = bid >> 3, bx = j & 7, by = k*16 + (j >> 3)
    // -> XCD k owns contiguous bands [16k, 16k+16) (256 output rows) with all
    // 8 col-blocks of each band: seam lines merge in one L2.
    const int bid = blockIdx.x;
    const int k_xcd = bid & 7;
    const int j = bid >> 3;
    const int bx = j & 7;
    const int by = (k_xcd << 4) | (j >> 3);

    // Block tile: output rows [R0, R0+16) (2 per ty), cols [C0, C0+256) (4 per tx).
    // Input needed: rows R0..R0+18 (19), cols C0..C0+258 (259) -> LDS [19][260].
    __shared__ float xs[19][260];

    const int tx = threadIdx.x;            // 0..63 (one wave per ty)
    const int ty = threadIdx.y;            // 0..7
    const int tid = ty * 64 + tx;
    const int R0 = by * 16;
    const int C0 = bx * 256;

#pragma unroll
    for (int it = 0; it < 10; ++it) {
        const int idx = tid + it * 512;
        if (idx < 19 * 259) {
            const int lr = idx / 259;
            const int lc = idx - lr * 259;
            const int gr = min(R0 + lr, XD - 1);
            const int gc = min(C0 + lc, XD - 1);
            xs[lr][lc] = x[gr * XD + gc];
        }
    }
    __syncthreads();

    const int fr  = R0 + 2 * ty;           // first output row (always even)
    const int fc0 = C0 + 4 * tx;           // first output col
    const int qy  = fr >> 1;               // pooled row
    const int pc0 = fc0 >> 1;              // first pooled col
    const bool rowsValid = (fr < HF);
    const bool cR = (fr  == HF - 2);       // site row 2 == 2046 -> clamp
    const bool cC = (fc0 == HF - 2);       // site cols >= 2046 -> clamp

    // 5x8 input window from LDS: rows 2ty..2ty+4, cols 4tx..4tx+7
    float win[5][8];
#pragma unroll
    for (int i = 0; i < 5; ++i) {
        const v4f a = *reinterpret_cast<const v4f*>(&xs[2 * ty + i][4 * tx]);
        const v4f b = *reinterpret_cast<const v4f*>(&xs[2 * ty + i][4 * tx + 4]);
        win[i][0] = a[0]; win[i][1] = a[1]; win[i][2] = a[2]; win[i][3] = a[3];
        win[i][4] = b[0]; win[i][5] = b[1]; win[i][6] = b[2]; win[i][7] = b[3];
    }

    // Suppression masks from D1 (ch4), D2 (ch5), bit-packed:
    // bit layout: m*8 + py*4 + px for m in {fd, sd, fdd, sdd}
    unsigned mb = 0;
    {
        float d1[3][5], d2[3][5];
        conv_pair<4, 5>(win, w, cR, cC, d1, d2);
#pragma unroll
        for (int py = 0; py < 2; ++py)
#pragma unroll
            for (int px = 0; px < 4; ++px) {
                const bool z0 = cR && (py == 0);
                const bool z1 = cC && (px == 0);
                const float a1 = d1[py][px], a2 = d2[py][px];
                const float s11 = z1 ? 0.f : d1[py][px + 1];
                const float s12 = z1 ? 0.f : d2[py][px + 1];
                const float s01 = z0 ? 0.f : d1[py + 1][px];
                const float s02 = z0 ? 0.f : d2[py + 1][px];
                const int base = py * 4 + px;
                mb |= (a1 * s11 <= THR ? 1u : 0u) << base;
                mb |= (a2 * s12 <= THR ? 1u : 0u) << (8 + base);
                mb |= (a1 * s01 <= THR ? 1u : 0u) << (16 + base);
                mb |= (a2 * s02 <= THR ? 1u : 0u) << (24 + base);
            }
    }

    float* __restrict__ mult   = out;
    float* __restrict__ pooled = out + (size_t)12 * HF * HF;

    // branch a: V1=ch0, H1=ch2 -> planes 0..5; branch b: oV1=ch1, oH1=ch3 -> 6..11
    branch_eval<0, 2, 0>(win, w, mb, cR, cC, rowsValid, fr, fc0, qy, pc0,
                         mult, pooled);
    branch_eval<1, 3, 6>(win, w, mb, cR, cC, rowsValid, fr, fc0, qy, pc0,
                         mult, pooled);
}

extern "C" void kernel_launch(void* const* d_in, const int* in_sizes, int n_in,
                              void* d_out, int out_size, void* d_ws, size_t ws_size,
                              hipStream_t stream) {
    const float* x = (const float*)d_in[0];
    const float* w = (const float*)d_in[1];
    float* out = (float*)d_out;
    (void)in_sizes; (void)n_in; (void)out_size; (void)d_ws; (void)ws_size;

    dim3 block(64, 8);
    dim3 grid(1024);   // remapped in-kernel to (8 col-blocks, 128 bands of 16 rows)
    hipLaunchKernelGGL(first_level_fused, grid, block, 0, stream, x, w, out);
}